// Round 14
// baseline (774.975 us; speedup 1.0000x reference)
//
#include <hip/hip_runtime.h>
#include <math.h>

// Problem constants
#define BATCH 1024
#define NA 10
#define NEN 10
#define NALY 9
#define NAG (BATCH*NA)          // 10240
#define NEE (NAG*NEN)           // 102400
#define NAE (NAG*NALY)          // 92160
#define EPSF 1e-5f

// f64 replicated qbn-sum buffers (16 replicas), at start of ws (double units)
#define DOFF_SE1 0
#define DOFF_SE2 1024
#define DOFF_SA1 2048
#define DOFF_SA2 3072
#define DOFF_SF1 4096
#define DOFF_SF2 5120
#define DOFF_SIE1 6144
#define DOFF_SIE2 7168
#define DOFF_SIA1 8192
#define DOFF_SIA2 9216
#define DOFF_SIE3 10240   // 16 replicas x stride 8 (one cache line each)
#define DOFF_SIA3 10368   // 16 replicas x stride 8
#define NDOUBLES 16384

__device__ __forceinline__ double sum16vd(const double* __restrict__ S, int ch) {
    double s = 0.0;
#pragma unroll
    for (int r = 0; r < 16; ++r) s += S[r*64 + ch];
    return s;
}
__device__ __forceinline__ double sum16sd8(const double* __restrict__ S) {
    double s = 0.0;
#pragma unroll
    for (int r = 0; r < 16; ++r) s += S[r*8];
    return s;
}
// qbn scale: s = fl32(sqrt(fl32(exact_mean) + eps))
__device__ __forceinline__ float qbn_s(const double* __restrict__ S, int ch, double invRows) {
    float m = (float)(sum16vd(S, ch)*invRows);
    return sqrtf(m + EPSF);
}
__device__ __forceinline__ void red_to_S(const double* red, double* S, int bid, int tid) {
    if (tid < 64) {
        double v = red[tid] + red[tid+64] + red[tid+128] + red[tid+192];
        atomicAdd(&S[(bid & 15)*64 + tid], v);
    }
}
// np-lattice pair mod^2: fl(fl(x0^2)+fl(x1^2)) (no FMA contraction)
__device__ __forceinline__ float pair_m2(float x0, float x1) {
    return __fadd_rn(__fmul_rn(x0,x0), __fmul_rn(x1,x1));
}

// ---- build_vec + layer1 GEMM; 8 ents/block, 4 ents/thread. Per-output
//      FP sequence identical to R10 (REVERSED k, FROZEN — feeds pool). ----
__global__ __launch_bounds__(256) void k_build_pair(
    const float* __restrict__ feats, const float* __restrict__ own,
    const float* __restrict__ W1, float* __restrict__ X,
    double* __restrict__ S1, int nEntPerAgent)
{
    __shared__ float wlds[19*64];
    __shared__ float g[8][19];
    __shared__ float pxy[8][2];
    __shared__ double red[256];
    int tid = threadIdx.x;
    for (int i = tid; i < 19*64; i += 256) wlds[i] = W1[i];
    if (tid < 152) {
        int el = tid / 19, chg = tid % 19;
        int ent = blockIdx.x*8 + el;
        const float* f = feats + (size_t)ent*9;
        int agent = ent / nEntPerAgent;
        float px = f[2], py = f[3];
        float pm = sqrtf(__fadd_rn(__fmul_rn(px,px), __fmul_rn(py,py)));
        float val;
        if (chg == 0) val = 1.f;
        else if (chg < 8) {
            int j = chg - 1;
            int fi = (j < 2) ? j : (j + 2);
            float o = f[fi];
            float om = sqrtf(__fmul_rn(__fmul_rn(2.0f,o),o));
            val = (pm == 0.f) ? 0.f : __fdiv_rn(om, pm);
        } else {
            float o = own[(size_t)agent*11 + (chg-8)];
            float t = __fmul_rn(o,o);
            float om = sqrtf(__fadd_rn(t,t));
            val = (pm == 0.f) ? 0.f : __fdiv_rn(om, pm);
        }
        g[el][chg] = val;
        if (chg == 0) { pxy[el][0] = px; pxy[el][1] = py; }
    }
    __syncthreads();
    int l = tid >> 7, c = (tid >> 6) & 1, ch = tid & 63;
    double lr = 0.0;
#pragma unroll
    for (int i = 0; i < 4; ++i) {
        int el = l + 2*i;
        int ent = blockIdx.x*8 + el;
        float pc = pxy[el][c];
        float acc = 0.f;
#pragma unroll
        for (int k = 18; k >= 0; --k) {            // REVERSED k (frozen)
            float ev = __fmul_rn(pc, g[el][k]);
            acc = fmaf(ev, wlds[k*64+ch], acc);
        }
        X[(size_t)ent*128 + c*64 + ch] = acc;
        lr += (double)acc * (double)acc;
    }
    red[tid] = lr;
    __syncthreads();
    red_to_S(red, S1, blockIdx.x, tid);
}

// ---- pair layer: qbn + qrelu + 64x64 GEMM; 16 rows/block, ch-vectorized.
//      Per-output fmaf chain identical to R10 (REVERSED k, FROZEN). ----
__global__ __launch_bounds__(256) void k_pair_layer(
    float* __restrict__ X, const double* __restrict__ Sin, double* __restrict__ Sout,
    const float* __restrict__ W, double invRows)
{
    __shared__ float wlds[4096];
    __shared__ float ybuf[16][132];   // [row][2*ch + p], padded
    __shared__ float ss[64];
    __shared__ double dredw[4][64];   // per-wave row-reduced stats
    int tid = threadIdx.x;
    for (int i = tid; i < 4096; i += 256) wlds[i] = W[i];
    if (tid < 64) ss[tid] = qbn_s(Sin, tid, invRows);
    __syncthreads();
    int rl = tid >> 4;
    int ch0 = (tid & 15) * 4;
    size_t row = (size_t)blockIdx.x*16 + rl;
    float4 xv0 = *(const float4*)&X[row*128 + ch0];
    float4 xv1 = *(const float4*)&X[row*128 + 64 + ch0];
    {
        float xs0[4] = {xv0.x,xv0.y,xv0.z,xv0.w};
        float xs1[4] = {xv1.x,xv1.y,xv1.z,xv1.w};
        float y0[4], y1[4];
#pragma unroll
        for (int i = 0; i < 4; ++i) {
            float s = ss[ch0+i];
            float u0 = xs0[i]/s, u1 = xs1[i]/s;
            float mod = sqrtf(pair_m2(u0,u1));
            float cf = mod / fmaxf(1.f, mod);
            y0[i] = __fmul_rn(u0,cf);
            y1[i] = __fmul_rn(u1,cf);
        }
        *(float4*)&ybuf[rl][2*ch0]     = make_float4(y0[0],y1[0],y0[1],y1[1]);
        *(float4*)&ybuf[rl][2*ch0 + 4] = make_float4(y0[2],y1[2],y0[3],y1[3]);
    }
    __syncthreads();
    float a0[4] = {0.f,0.f,0.f,0.f};
    float a1[4] = {0.f,0.f,0.f,0.f};
#pragma unroll
    for (int k = 63; k >= 1; k -= 2) {           // REVERSED k, unroll 2
        float4 wk  = *(const float4*)&wlds[k*64 + ch0];
        float4 wk1 = *(const float4*)&wlds[(k-1)*64 + ch0];
        float4 y4  = *(const float4*)&ybuf[rl][2*k - 2]; // (k-1,p0)(k-1,p1)(k,p0)(k,p1)
        float wkv[4]  = {wk.x,wk.y,wk.z,wk.w};
        float wk1v[4] = {wk1.x,wk1.y,wk1.z,wk1.w};
#pragma unroll
        for (int i = 0; i < 4; ++i) {
            a0[i] = fmaf(y4.z, wkv[i], a0[i]);
            a1[i] = fmaf(y4.w, wkv[i], a1[i]);
        }
#pragma unroll
        for (int i = 0; i < 4; ++i) {
            a0[i] = fmaf(y4.x, wk1v[i], a0[i]);
            a1[i] = fmaf(y4.y, wk1v[i], a1[i]);
        }
    }
    *(float4*)&X[row*128 + ch0]      = make_float4(a0[0],a0[1],a0[2],a0[3]);
    *(float4*)&X[row*128 + 64 + ch0] = make_float4(a1[0],a1[1],a1[2],a1[3]);
    // wave-level f64 row reduction (lane bits 4,5 = row within wave)
    {
        int wv = tid >> 6;
#pragma unroll
        for (int i = 0; i < 4; ++i) {
            double d = (double)a0[i]*a0[i] + (double)a1[i]*a1[i];
            d += __shfl_xor(d, 16, 64);
            d += __shfl_xor(d, 32, 64);
            if ((tid & 48) == 0) dredw[wv][ch0+i] = d;
        }
    }
    __syncthreads();
    if (tid < 64) {
        double v = dredw[0][tid] + dredw[1][tid] + dredw[2][tid] + dredw[3][tid];
        atomicAdd(&Sout[(blockIdx.x & 15)*64 + tid], v);
    }
}

// ---- Finalize (E only): y = qrelu(qbn(x)), in place, b128. Ops identical. --
__global__ __launch_bounds__(256) void k_finalize_pair(
    float* __restrict__ X, const double* __restrict__ S2, double invRows)
{
    __shared__ float ss[64];
    if (threadIdx.x < 64) ss[threadIdx.x] = qbn_s(S2, threadIdx.x, invRows);
    int t = blockIdx.x*256 + threadIdx.x;
    int rl = t >> 4;              // (ent*2 + c) row index
    int ch0 = (t & 15) * 4;
    size_t base    = (size_t)rl*64 + ch0;
    size_t partner = (size_t)(rl ^ 1)*64 + ch0;
    float4 xv  = *(const float4*)&X[base];
    float4 xov = *(const float4*)&X[partner];
    __syncthreads();
    float xs[4]  = {xv.x,xv.y,xv.z,xv.w};
    float xos[4] = {xov.x,xov.y,xov.z,xov.w};
    float r[4];
#pragma unroll
    for (int i = 0; i < 4; ++i) {
        float s = ss[ch0+i];
        float u  = xs[i]/s;
        float uo = xos[i]/s;
        int c = rl & 1;
        float u0 = (c==0) ? u : uo, u1 = (c==0) ? uo : u;
        float mod = sqrtf(pair_m2(u0,u1));
        float cf = mod / fmaxf(1.f, mod);
        r[i] = __fmul_rn(u, cf);
    }
    *(float4*)&X[base] = make_float4(r[0],r[1],r[2],r[3]);
}

// ---- Pool + f1 GEMM, ally finalize fused (identical op sequence). ----
__global__ __launch_bounds__(256) void k_pool_f1(
    const float* __restrict__ XE, const float* __restrict__ XAraw,
    const double* __restrict__ SA2, double invRa,
    const float* __restrict__ Wf1, float* __restrict__ F1, double* __restrict__ Sf1)
{
    __shared__ float wlds[4096];
    __shared__ float v[4][2][64];
    __shared__ float ssa[64];
    __shared__ double red[256];
    int tid = threadIdx.x;
    for (int i = tid; i < 4096; i += 256) wlds[i] = Wf1[i];
    if (tid < 64) ssa[tid] = qbn_s(SA2, tid, invRa);
    __syncthreads();
    int grp = tid>>6, ch = tid&63;
    int agent = blockIdx.x*4 + grp;
    float best = -1.f, v0 = 0.f, v1 = 0.f;
    for (int e = 0; e < NEN; ++e) {
        size_t b = (size_t)(agent*NEN+e)*128;
        float x0 = XE[b+ch], x1 = XE[b+64+ch];
        float m2 = pair_m2(x0,x1);
        if (m2 > best) { best = m2; v0 = x0; v1 = x1; }
    }
    float sa = ssa[ch];
    for (int l = 0; l < NALY; ++l) {
        size_t b = (size_t)(agent*NALY+l)*128;
        float r0 = XAraw[b+ch], r1 = XAraw[b+64+ch];
        float u0 = r0/sa, u1 = r1/sa;
        float modf = sqrtf(pair_m2(u0,u1));
        float cff = modf / fmaxf(1.f, modf);
        float x0 = __fmul_rn(u0,cff), x1 = __fmul_rn(u1,cff);
        float m2 = pair_m2(x0,x1);
        if (m2 > best) { best = m2; v0 = x0; v1 = x1; }
    }
    v[grp][0][ch] = v0; v[grp][1][ch] = v1;
    __syncthreads();
    float a0 = 0.f, a1 = 0.f;
#pragma unroll
    for (int k = 0; k < 64; ++k) {
        float w = wlds[k*64+ch];
        a0 = fmaf(v[grp][0][k], w, a0);
        a1 = fmaf(v[grp][1][k], w, a1);
    }
    F1[(size_t)agent*128+ch] = a0; F1[(size_t)agent*128+64+ch] = a1;
    red[tid] = (double)a0*a0 + (double)a1*a1;
    __syncthreads();
    red_to_S(red, Sf1, blockIdx.x, tid);
}

// ---- vf finalize + SFb + VT = vf @ W1top for both imp chains. ----
__global__ __launch_bounds__(256) void k_vf_vtop(
    const float* __restrict__ F1, const double* __restrict__ Sf2,
    float* __restrict__ SFb,
    const float* __restrict__ Wie1, const float* __restrict__ Wia1,
    float* __restrict__ VTie, float* __restrict__ VTia, double invRows)
{
    __shared__ float wie[4096];
    __shared__ float wia[4096];
    __shared__ float vf[4][2][64];
    int tid = threadIdx.x;
    for (int i = tid; i < 4096; i += 256) { wie[i] = Wie1[i]; wia[i] = Wia1[i]; }
    int grp = tid>>6, ch = tid&63;
    int agent = blockIdx.x*4 + grp;
    float x0 = F1[(size_t)agent*128+ch], x1 = F1[(size_t)agent*128+64+ch];
    float s = qbn_s(Sf2, ch, invRows);
    float u0 = x0/s, u1 = x1/s;
    float mod = sqrtf(pair_m2(u0,u1));
    float cf = mod / fmaxf(1.f, mod);
    float y0 = __fmul_rn(u0,cf), y1 = __fmul_rn(u1,cf);
    vf[grp][0][ch] = y0; vf[grp][1][ch] = y1;
    SFb[(size_t)agent*64+ch] = pair_m2(y0,y1);
    __syncthreads();
    float a0=0.f,a1=0.f,b0=0.f,b1=0.f;
#pragma unroll
    for (int k = 0; k < 64; ++k) {
        float f0 = vf[grp][0][k], f1 = vf[grp][1][k];
        a0 = fmaf(f0, wie[k*64+ch], a0); a1 = fmaf(f1, wie[k*64+ch], a1);
        b0 = fmaf(f0, wia[k*64+ch], b0); b1 = fmaf(f1, wia[k*64+ch], b1);
    }
    VTie[(size_t)agent*128+ch] = a0; VTie[(size_t)agent*128+64+ch] = a1;
    VTia[(size_t)agent*128+ch] = b0; VTia[(size_t)agent*128+64+ch] = b1;
}

// ---- imp layer1: XI = VT + XE @ W1bot; 8 ents/block, ch-vectorized. ----
__global__ __launch_bounds__(256) void k_imp1(
    const float* __restrict__ XE, const float* __restrict__ VT,
    const float* __restrict__ W1, float* __restrict__ XI, double* __restrict__ S1)
{
    __shared__ float wlds[4096];
    __shared__ float xt[16][68];      // 16 rows=(ent,c) x 64 k, padded
    __shared__ double dredw[4][64];
    int tid = threadIdx.x;
    for (int i = tid; i < 4096; i += 256) wlds[i] = W1[4096 + i];
    {
        int r = tid >> 4;             // 256 float4 = 16 rows x 16 quads
        int kq = (tid & 15) * 4;
        float4 t4 = *(const float4*)&XE[(size_t)blockIdx.x*1024 + tid*4];
        *(float4*)&xt[r][kq] = t4;
    }
    __syncthreads();
    int rl = tid >> 4;
    int ch0 = (tid & 15) * 4;
    int ent = blockIdx.x*8 + (rl >> 1);
    int c = rl & 1;
    int agent = ent / NEN;
    float4 vt = *(const float4*)&VT[(size_t)agent*128 + c*64 + ch0];
    float acc[4] = {vt.x, vt.y, vt.z, vt.w};
#pragma unroll
    for (int k = 0; k < 64; k += 4) {
        float4 x4 = *(const float4*)&xt[rl][k];
        float xk[4] = {x4.x, x4.y, x4.z, x4.w};
#pragma unroll
        for (int kk = 0; kk < 4; ++kk) {
            float4 w4 = *(const float4*)&wlds[(k+kk)*64 + ch0];
            acc[0] = fmaf(xk[kk], w4.x, acc[0]);
            acc[1] = fmaf(xk[kk], w4.y, acc[1]);
            acc[2] = fmaf(xk[kk], w4.z, acc[2]);
            acc[3] = fmaf(xk[kk], w4.w, acc[3]);
        }
    }
    *(float4*)&XI[(size_t)ent*128 + c*64 + ch0] = make_float4(acc[0],acc[1],acc[2],acc[3]);
    {
        int wv = tid >> 6;
#pragma unroll
        for (int i = 0; i < 4; ++i) {
            double d = (double)acc[i]*acc[i];
            d += __shfl_xor(d, 16, 64);
            d += __shfl_xor(d, 32, 64);
            if ((tid & 48) == 0) dredw[wv][ch0+i] = d;
        }
    }
    __syncthreads();
    if (tid < 64) {
        double v = dredw[0][tid] + dredw[1][tid] + dredw[2][tid] + dredw[3][tid];
        atomicAdd(&S1[(blockIdx.x & 15)*64 + tid], v);
    }
}

// ---- imp layer3: 16 ents/block; one strided atomic per block. ----
__global__ __launch_bounds__(256) void k_imp3(
    const float* __restrict__ XI, const double* __restrict__ S2,
    const float* __restrict__ W3, float* __restrict__ Z, double* __restrict__ S3,
    double invRows)
{
    __shared__ float ss[64];
    __shared__ double red4[4];
    int tid = threadIdx.x; int grp = tid>>6, ch = tid&63;
    if (tid < 64) ss[tid] = qbn_s(S2, tid, invRows);
    __syncthreads();
    float s = ss[ch];
    double w3 = (double)W3[ch];
    double lr3 = 0.0;
#pragma unroll
    for (int i = 0; i < 4; ++i) {
        int ent = blockIdx.x*16 + grp + 4*i;
        float x0 = XI[(size_t)ent*128+ch], x1 = XI[(size_t)ent*128+64+ch];
        float u0 = x0/s, u1 = x1/s;
        float mod = sqrtf(pair_m2(u0,u1));
        float cf = mod / fmaxf(1.f, mod);
        double v0 = (double)__fmul_rn(u0,cf) * w3;
        double v1 = (double)__fmul_rn(u1,cf) * w3;
#pragma unroll
        for (int m = 1; m < 64; m <<= 1) { v0 += __shfl_xor(v0,m,64); v1 += __shfl_xor(v1,m,64); }
        if (ch == 0) {
            float z0 = (float)v0, z1 = (float)v1;
            Z[(size_t)ent*2] = z0; Z[(size_t)ent*2+1] = z1;
            lr3 += (double)z0*z0 + (double)z1*z1;
        }
    }
    if (ch == 0) red4[grp] = lr3;
    __syncthreads();
    if (tid == 0) atomicAdd(&S3[(blockIdx.x & 15)*8], red4[0]+red4[1]+red4[2]+red4[3]);
}

// ---- move_vec + oaq head + output cols 0..5. ----
__global__ __launch_bounds__(256) void k_final_small(
    const float* __restrict__ Zie, const float* __restrict__ Zia,
    const double* __restrict__ Sie3, const double* __restrict__ Sia3,
    const float* __restrict__ SFb,
    const float* __restrict__ Woa1, const float* __restrict__ boa1,
    const float* __restrict__ Woa2, const float* __restrict__ boa2,
    float* __restrict__ out, double invRows)
{
    __shared__ float sflds[4][64];
    int tid = threadIdx.x; int grp = tid>>6, ch = tid&63;
    int agent = blockIdx.x*4 + grp;
    float sie = sqrtf((float)(sum16sd8(Sie3)*invRows) + EPSF);
    float sia = sqrtf((float)(sum16sd8(Sia3)*invRows) + EPSF);
    double pv0 = 0.0, pv1 = 0.0;
    if (ch < NEN) {
        int ent = agent*NEN + ch;
        float z0 = Zie[(size_t)ent*2]/sie, z1 = Zie[(size_t)ent*2+1]/sie;
        float mod = sqrtf(pair_m2(z0,z1)); float cf = mod/fmaxf(1.f,mod);
        pv0 = (double)__fmul_rn(z0,cf); pv1 = (double)__fmul_rn(z1,cf);
        z0 = Zia[(size_t)ent*2]/sia; z1 = Zia[(size_t)ent*2+1]/sia;
        mod = sqrtf(pair_m2(z0,z1)); cf = mod/fmaxf(1.f,mod);
        pv0 += (double)__fmul_rn(z0,cf); pv1 += (double)__fmul_rn(z1,cf);
    }
#pragma unroll
    for (int m = 1; m < 64; m <<= 1) { pv0 += __shfl_xor(pv0,m,64); pv1 += __shfl_xor(pv1,m,64); }
    sflds[grp][ch] = SFb[(size_t)agent*64+ch];
    __syncthreads();
    double hd = (double)boa1[ch];
#pragma unroll
    for (int k = 0; k < 64; ++k) hd += (double)sflds[grp][k]*(double)Woa1[k*64+ch];
    float h = fmaxf((float)hd, 0.f);
    double q0 = (double)h*(double)Woa2[ch*3+0];
    double q1 = (double)h*(double)Woa2[ch*3+1];
    double q2 = (double)h*(double)Woa2[ch*3+2];
#pragma unroll
    for (int m = 1; m < 64; m <<= 1) { q0 += __shfl_xor(q0,m,64); q1 += __shfl_xor(q1,m,64); q2 += __shfl_xor(q2,m,64); }
    if (ch == 0) {
        float oaq0 = (float)(q0 + (double)boa2[0]);
        float oaq1 = (float)(q1 + (double)boa2[1]);
        float mmq  = (float)(q2 + (double)boa2[2]);
        float mv0 = (float)pv0, mv1 = (float)pv1;
        float* o = out + (size_t)agent*16;
        o[0] = oaq0; o[1] = oaq1;
        o[2] = mmq + mv1; o[3] = mmq - mv1;
        o[4] = mmq + mv0; o[5] = mmq - mv0;
    }
}

// ---- Attention MLP (128->128->64->1), f32, 16 rows/block, reg tiles. ----
__global__ __launch_bounds__(256) void k_attn(
    const float* __restrict__ SFb, const float* __restrict__ XE,
    const float* __restrict__ W1, const float* __restrict__ b1,
    const float* __restrict__ W2, const float* __restrict__ b2,
    const float* __restrict__ W3, const float* __restrict__ b3,
    float* __restrict__ out)
{
    __shared__ float atf[16][132];
    __shared__ float h1[16][132];
    __shared__ float h2[16][68];
    int tid = threadIdx.x;
    int row0 = blockIdx.x*16;
#pragma unroll
    for (int i = 0; i < 8; ++i) {
        int idx = tid + i*256; int r = idx>>7; int j = idx&127;
        int ent = row0 + r; int agent = ent/NEN;
        float v;
        if (j < 64) v = SFb[(size_t)agent*64+j];
        else {
            float x0 = XE[(size_t)ent*128 + (j-64)];
            float x1 = XE[(size_t)ent*128 + 64 + (j-64)];
            v = pair_m2(x0,x1);
        }
        atf[r][j] = v;
    }
    __syncthreads();
    {   // layer1: 16 rows x 128 cols, tile 2 rows x 4 cols
        int rg = tid >> 5;            // 0..7 -> rows rg*2..+1
        int j0 = (tid & 31) * 4;
        float4 bb = *(const float4*)&b1[j0];
        float acc[2][4];
#pragma unroll
        for (int r = 0; r < 2; ++r) {
            acc[r][0]=bb.x; acc[r][1]=bb.y; acc[r][2]=bb.z; acc[r][3]=bb.w;
        }
        for (int k = 0; k < 128; k += 4) {
            float4 a0 = *(const float4*)&atf[rg*2][k];
            float4 a1 = *(const float4*)&atf[rg*2+1][k];
            float av0[4] = {a0.x,a0.y,a0.z,a0.w};
            float av1[4] = {a1.x,a1.y,a1.z,a1.w};
#pragma unroll
            for (int kk = 0; kk < 4; ++kk) {
                float4 w4 = *(const float4*)&W1[(k+kk)*128 + j0];
                acc[0][0] = fmaf(av0[kk], w4.x, acc[0][0]);
                acc[0][1] = fmaf(av0[kk], w4.y, acc[0][1]);
                acc[0][2] = fmaf(av0[kk], w4.z, acc[0][2]);
                acc[0][3] = fmaf(av0[kk], w4.w, acc[0][3]);
                acc[1][0] = fmaf(av1[kk], w4.x, acc[1][0]);
                acc[1][1] = fmaf(av1[kk], w4.y, acc[1][1]);
                acc[1][2] = fmaf(av1[kk], w4.z, acc[1][2]);
                acc[1][3] = fmaf(av1[kk], w4.w, acc[1][3]);
            }
        }
#pragma unroll
        for (int r = 0; r < 2; ++r)
            *(float4*)&h1[rg*2+r][j0] = make_float4(fmaxf(acc[r][0],0.f), fmaxf(acc[r][1],0.f),
                                                   fmaxf(acc[r][2],0.f), fmaxf(acc[r][3],0.f));
    }
    __syncthreads();
    {   // layer2: 16 rows x 64 cols, tile 1 row x 4 cols
        int rr = tid >> 4;            // 0..15 rows
        int j0 = (tid & 15) * 4;
        float4 bb = *(const float4*)&b2[j0];
        float acc[4] = {bb.x, bb.y, bb.z, bb.w};
        for (int k = 0; k < 128; k += 4) {
            float4 p = *(const float4*)&h1[rr][k];
            float pv[4] = {p.x,p.y,p.z,p.w};
#pragma unroll
            for (int kk = 0; kk < 4; ++kk) {
                float4 w4 = *(const float4*)&W2[(k+kk)*64 + j0];
                acc[0] = fmaf(pv[kk], w4.x, acc[0]);
                acc[1] = fmaf(pv[kk], w4.y, acc[1]);
                acc[2] = fmaf(pv[kk], w4.z, acc[2]);
                acc[3] = fmaf(pv[kk], w4.w, acc[3]);
            }
        }
        *(float4*)&h2[rr][j0] = make_float4(fmaxf(acc[0],0.f), fmaxf(acc[1],0.f),
                                            fmaxf(acc[2],0.f), fmaxf(acc[3],0.f));
    }
    __syncthreads();
    {   // layer3: 16 rows, 16 lanes/row
        int r3 = tid >> 4, l3 = tid & 15;
        float s = 0.f;
#pragma unroll
        for (int q = 0; q < 4; ++q) s = fmaf(h2[r3][l3 + 16*q], W3[l3 + 16*q], s);
#pragma unroll
        for (int m = 1; m < 16; m <<= 1) s += __shfl_xor(s, m, 64);
        if (l3 == 0) {
            int ent = row0 + r3; int agent = ent/NEN; int e = ent%NEN;
            out[(size_t)agent*16 + 6 + e] = s + b3[0];
        }
    }
}

extern "C" void kernel_launch(void* const* d_in, const int* in_sizes, int n_in,
                              void* d_out, int out_size, void* d_ws, size_t ws_size,
                              hipStream_t stream) {
    const float* own  = (const float*)d_in[0];
    const float* ef   = (const float*)d_in[1];
    const float* af   = (const float*)d_in[2];
    const float* W_e1 = (const float*)d_in[3];
    const float* W_e2 = (const float*)d_in[4];
    const float* W_a1 = (const float*)d_in[5];
    const float* W_a2 = (const float*)d_in[6];
    const float* W_f1 = (const float*)d_in[7];
    const float* W_f2 = (const float*)d_in[8];
    const float* W_ie1= (const float*)d_in[9];
    const float* W_ie2= (const float*)d_in[10];
    const float* W_ie3= (const float*)d_in[11];
    const float* W_ia1= (const float*)d_in[12];
    const float* W_ia2= (const float*)d_in[13];
    const float* W_ia3= (const float*)d_in[14];
    const float* W_oa1= (const float*)d_in[15];
    const float* b_oa1= (const float*)d_in[16];
    const float* W_oa2= (const float*)d_in[17];
    const float* b_oa2= (const float*)d_in[18];
    const float* W_at1= (const float*)d_in[19];
    const float* b_at1= (const float*)d_in[20];
    const float* W_at2= (const float*)d_in[21];
    const float* b_at2= (const float*)d_in[22];
    const float* W_at3= (const float*)d_in[23];
    const float* b_at3= (const float*)d_in[24];
    float* out = (float*)d_out;
    float* wsf = (float*)d_ws;
    double* Sd = (double*)d_ws;

    size_t o = (size_t)NDOUBLES*2;
    float*  X_E  = wsf + o; o += (size_t)NEE*128;
    float*  X_A  = wsf + o; o += (size_t)NAE*128;
    float*  F1   = wsf + o; o += (size_t)NAG*128;
    float*  SFb  = wsf + o; o += (size_t)NAG*64;
    float*  VT_IE = wsf + o; o += (size_t)NAG*128;
    float*  VT_IA = wsf + o; o += (size_t)NAG*128;
    float*  XI   = wsf + o; o += (size_t)NEE*128;
    float*  Z_IE = wsf + o; o += (size_t)NEE*2;
    float*  Z_IA = wsf + o; o += (size_t)NEE*2;

    double* S_E1 = Sd + DOFF_SE1;  double* S_E2 = Sd + DOFF_SE2;
    double* S_A1 = Sd + DOFF_SA1;  double* S_A2 = Sd + DOFF_SA2;
    double* S_F1 = Sd + DOFF_SF1;  double* S_F2 = Sd + DOFF_SF2;
    double* S_IE1= Sd + DOFF_SIE1; double* S_IE2= Sd + DOFF_SIE2;
    double* S_IA1= Sd + DOFF_SIA1; double* S_IA2= Sd + DOFF_SIA2;
    double* S_IE3= Sd + DOFF_SIE3; double* S_IA3= Sd + DOFF_SIA3;

    const double invRe = 1.0/(double)(NEE*2);
    const double invRa = 1.0/(double)(NAE*2);
    const double invRf = 1.0/(double)(NAG*2);

    hipMemsetAsync(Sd, 0, (size_t)NDOUBLES*sizeof(double), stream);

    k_build_pair<<<NEE/8, 256, 0, stream>>>(ef, own, W_e1, X_E, S_E1, NEN);
    k_build_pair<<<NAE/8, 256, 0, stream>>>(af, own, W_a1, X_A, S_A1, NALY);
    k_pair_layer<<<NEE/16, 256, 0, stream>>>(X_E, S_E1, S_E2, W_e2, invRe);
    k_pair_layer<<<NAE/16, 256, 0, stream>>>(X_A, S_A1, S_A2, W_a2, invRa);
    k_finalize_pair<<<NEE*32/256, 256, 0, stream>>>(X_E, S_E2, invRe);
    k_pool_f1<<<NAG/4, 256, 0, stream>>>(X_E, X_A, S_A2, invRa, W_f1, F1, S_F1);
    k_pair_layer<<<NAG/16, 256, 0, stream>>>(F1, S_F1, S_F2, W_f2, invRf);
    k_vf_vtop<<<NAG/4, 256, 0, stream>>>(F1, S_F2, SFb, W_ie1, W_ia1, VT_IE, VT_IA, invRf);
    // e-importance chain
    k_imp1<<<NEE/8, 256, 0, stream>>>(X_E, VT_IE, W_ie1, XI, S_IE1);
    k_pair_layer<<<NEE/16, 256, 0, stream>>>(XI, S_IE1, S_IE2, W_ie2, invRe);
    k_imp3<<<NEE/16, 256, 0, stream>>>(XI, S_IE2, W_ie3, Z_IE, S_IE3, invRe);
    // a-importance chain (same cat input; XI reused)
    k_imp1<<<NEE/8, 256, 0, stream>>>(X_E, VT_IA, W_ia1, XI, S_IA1);
    k_pair_layer<<<NEE/16, 256, 0, stream>>>(XI, S_IA1, S_IA2, W_ia2, invRe);
    k_imp3<<<NEE/16, 256, 0, stream>>>(XI, S_IA2, W_ia3, Z_IA, S_IA3, invRe);

    k_final_small<<<NAG/4, 256, 0, stream>>>(Z_IE, Z_IA, S_IE3, S_IA3, SFb,
                                             W_oa1, b_oa1, W_oa2, b_oa2, out, invRe);
    k_attn<<<NEE/16, 256, 0, stream>>>(SFb, X_E, W_at1, b_at1, W_at2, b_at2,
                                       W_at3, b_at3, out);
}

// Round 15
// 690.948 us; speedup vs baseline: 1.1216x; 1.1216x over previous
//
#include <hip/hip_runtime.h>
#include <math.h>

// Problem constants
#define BATCH 1024
#define NA 10
#define NEN 10
#define NALY 9
#define NAG (BATCH*NA)          // 10240
#define NEE (NAG*NEN)           // 102400
#define NAE (NAG*NALY)          // 92160
#define EPSF 1e-5f

// f64 replicated qbn-sum buffers (16 replicas), at start of ws (double units)
#define DOFF_SE1 0
#define DOFF_SE2 1024
#define DOFF_SA1 2048
#define DOFF_SA2 3072
#define DOFF_SF1 4096
#define DOFF_SF2 5120
#define DOFF_SIE1 6144
#define DOFF_SIE2 7168
#define DOFF_SIA1 8192
#define DOFF_SIA2 9216
#define DOFF_SIE3 10240   // 16 replicas x stride 8 (one cache line each)
#define DOFF_SIA3 10368   // 16 replicas x stride 8
#define NDOUBLES 16384

__device__ __forceinline__ double sum16vd(const double* __restrict__ S, int ch) {
    double s = 0.0;
#pragma unroll
    for (int r = 0; r < 16; ++r) s += S[r*64 + ch];
    return s;
}
__device__ __forceinline__ double sum16sd8(const double* __restrict__ S) {
    double s = 0.0;
#pragma unroll
    for (int r = 0; r < 16; ++r) s += S[r*8];
    return s;
}
// qbn scale: s = fl32(sqrt(fl32(exact_mean) + eps))
__device__ __forceinline__ float qbn_s(const double* __restrict__ S, int ch, double invRows) {
    float m = (float)(sum16vd(S, ch)*invRows);
    return sqrtf(m + EPSF);
}
__device__ __forceinline__ void red_to_S(const double* red, double* S, int bid, int tid) {
    if (tid < 64) {
        double v = red[tid] + red[tid+64] + red[tid+128] + red[tid+192];
        atomicAdd(&S[(bid & 15)*64 + tid], v);
    }
}
// np-lattice pair mod^2: fl(fl(x0^2)+fl(x1^2)) (no FMA contraction)
__device__ __forceinline__ float pair_m2(float x0, float x1) {
    return __fadd_rn(__fmul_rn(x0,x0), __fmul_rn(x1,x1));
}

// ---- build_vec + layer1 GEMM; 8 ents/block, 4 ents/thread. Per-output
//      FP sequence identical to R10 (REVERSED k, FROZEN — feeds pool). ----
__global__ __launch_bounds__(256) void k_build_pair(
    const float* __restrict__ feats, const float* __restrict__ own,
    const float* __restrict__ W1, float* __restrict__ X,
    double* __restrict__ S1, int nEntPerAgent)
{
    __shared__ float wlds[19*64];
    __shared__ float g[8][19];
    __shared__ float pxy[8][2];
    __shared__ double red[256];
    int tid = threadIdx.x;
    for (int i = tid; i < 19*64; i += 256) wlds[i] = W1[i];
    if (tid < 152) {
        int el = tid / 19, chg = tid % 19;
        int ent = blockIdx.x*8 + el;
        const float* f = feats + (size_t)ent*9;
        int agent = ent / nEntPerAgent;
        float px = f[2], py = f[3];
        float pm = sqrtf(__fadd_rn(__fmul_rn(px,px), __fmul_rn(py,py)));
        float val;
        if (chg == 0) val = 1.f;
        else if (chg < 8) {
            int j = chg - 1;
            int fi = (j < 2) ? j : (j + 2);
            float o = f[fi];
            float om = sqrtf(__fmul_rn(__fmul_rn(2.0f,o),o));
            val = (pm == 0.f) ? 0.f : __fdiv_rn(om, pm);
        } else {
            float o = own[(size_t)agent*11 + (chg-8)];
            float t = __fmul_rn(o,o);
            float om = sqrtf(__fadd_rn(t,t));
            val = (pm == 0.f) ? 0.f : __fdiv_rn(om, pm);
        }
        g[el][chg] = val;
        if (chg == 0) { pxy[el][0] = px; pxy[el][1] = py; }
    }
    __syncthreads();
    int l = tid >> 7, c = (tid >> 6) & 1, ch = tid & 63;
    double lr = 0.0;
#pragma unroll
    for (int i = 0; i < 4; ++i) {
        int el = l + 2*i;
        int ent = blockIdx.x*8 + el;
        float pc = pxy[el][c];
        float acc = 0.f;
#pragma unroll
        for (int k = 18; k >= 0; --k) {            // REVERSED k (frozen)
            float ev = __fmul_rn(pc, g[el][k]);
            acc = fmaf(ev, wlds[k*64+ch], acc);
        }
        X[(size_t)ent*128 + c*64 + ch] = acc;
        lr += (double)acc * (double)acc;
    }
    red[tid] = lr;
    __syncthreads();
    red_to_S(red, S1, blockIdx.x, tid);
}

// ---- pair layer: qbn + qrelu + 64x64 GEMM; 16 rows/block, ch-vectorized.
//      Per-output fmaf chain identical to R10 (REVERSED k, FROZEN). ----
__global__ __launch_bounds__(256) void k_pair_layer(
    float* __restrict__ X, const double* __restrict__ Sin, double* __restrict__ Sout,
    const float* __restrict__ W, double invRows)
{
    __shared__ float wlds[4096];
    __shared__ float ybuf[16][132];   // [row][2*ch + p], padded
    __shared__ float ss[64];
    __shared__ double dredw[4][64];   // per-wave row-reduced stats
    int tid = threadIdx.x;
    for (int i = tid; i < 4096; i += 256) wlds[i] = W[i];
    if (tid < 64) ss[tid] = qbn_s(Sin, tid, invRows);
    __syncthreads();
    int rl = tid >> 4;
    int ch0 = (tid & 15) * 4;
    size_t row = (size_t)blockIdx.x*16 + rl;
    float4 xv0 = *(const float4*)&X[row*128 + ch0];
    float4 xv1 = *(const float4*)&X[row*128 + 64 + ch0];
    {
        float xs0[4] = {xv0.x,xv0.y,xv0.z,xv0.w};
        float xs1[4] = {xv1.x,xv1.y,xv1.z,xv1.w};
        float y0[4], y1[4];
#pragma unroll
        for (int i = 0; i < 4; ++i) {
            float s = ss[ch0+i];
            float u0 = xs0[i]/s, u1 = xs1[i]/s;
            float mod = sqrtf(pair_m2(u0,u1));
            float cf = mod / fmaxf(1.f, mod);
            y0[i] = __fmul_rn(u0,cf);
            y1[i] = __fmul_rn(u1,cf);
        }
        *(float4*)&ybuf[rl][2*ch0]     = make_float4(y0[0],y1[0],y0[1],y1[1]);
        *(float4*)&ybuf[rl][2*ch0 + 4] = make_float4(y0[2],y1[2],y0[3],y1[3]);
    }
    __syncthreads();
    float a0[4] = {0.f,0.f,0.f,0.f};
    float a1[4] = {0.f,0.f,0.f,0.f};
#pragma unroll
    for (int k = 63; k >= 1; k -= 2) {           // REVERSED k, unroll 2
        float4 wk  = *(const float4*)&wlds[k*64 + ch0];
        float4 wk1 = *(const float4*)&wlds[(k-1)*64 + ch0];
        float4 y4  = *(const float4*)&ybuf[rl][2*k - 2]; // (k-1,p0)(k-1,p1)(k,p0)(k,p1)
        float wkv[4]  = {wk.x,wk.y,wk.z,wk.w};
        float wk1v[4] = {wk1.x,wk1.y,wk1.z,wk1.w};
#pragma unroll
        for (int i = 0; i < 4; ++i) {
            a0[i] = fmaf(y4.z, wkv[i], a0[i]);
            a1[i] = fmaf(y4.w, wkv[i], a1[i]);
        }
#pragma unroll
        for (int i = 0; i < 4; ++i) {
            a0[i] = fmaf(y4.x, wk1v[i], a0[i]);
            a1[i] = fmaf(y4.y, wk1v[i], a1[i]);
        }
    }
    *(float4*)&X[row*128 + ch0]      = make_float4(a0[0],a0[1],a0[2],a0[3]);
    *(float4*)&X[row*128 + 64 + ch0] = make_float4(a1[0],a1[1],a1[2],a1[3]);
    // wave-level f64 row reduction (lane bits 4,5 = row within wave)
    {
        int wv = tid >> 6;
#pragma unroll
        for (int i = 0; i < 4; ++i) {
            double d = (double)a0[i]*a0[i] + (double)a1[i]*a1[i];
            d += __shfl_xor(d, 16, 64);
            d += __shfl_xor(d, 32, 64);
            if ((tid & 48) == 0) dredw[wv][ch0+i] = d;
        }
    }
    __syncthreads();
    if (tid < 64) {
        double v = dredw[0][tid] + dredw[1][tid] + dredw[2][tid] + dredw[3][tid];
        atomicAdd(&Sout[(blockIdx.x & 15)*64 + tid], v);
    }
}

// ---- Finalize (E only): y = qrelu(qbn(x)), in place, b128. Ops identical. --
__global__ __launch_bounds__(256) void k_finalize_pair(
    float* __restrict__ X, const double* __restrict__ S2, double invRows)
{
    __shared__ float ss[64];
    if (threadIdx.x < 64) ss[threadIdx.x] = qbn_s(S2, threadIdx.x, invRows);
    int t = blockIdx.x*256 + threadIdx.x;
    int rl = t >> 4;              // (ent*2 + c) row index
    int ch0 = (t & 15) * 4;
    size_t base    = (size_t)rl*64 + ch0;
    size_t partner = (size_t)(rl ^ 1)*64 + ch0;
    float4 xv  = *(const float4*)&X[base];
    float4 xov = *(const float4*)&X[partner];
    __syncthreads();
    float xs[4]  = {xv.x,xv.y,xv.z,xv.w};
    float xos[4] = {xov.x,xov.y,xov.z,xov.w};
    float r[4];
#pragma unroll
    for (int i = 0; i < 4; ++i) {
        float s = ss[ch0+i];
        float u  = xs[i]/s;
        float uo = xos[i]/s;
        int c = rl & 1;
        float u0 = (c==0) ? u : uo, u1 = (c==0) ? uo : u;
        float mod = sqrtf(pair_m2(u0,u1));
        float cf = mod / fmaxf(1.f, mod);
        r[i] = __fmul_rn(u, cf);
    }
    *(float4*)&X[base] = make_float4(r[0],r[1],r[2],r[3]);
}

// ---- Pool + f1 GEMM, ally finalize fused (identical op sequence). ----
__global__ __launch_bounds__(256) void k_pool_f1(
    const float* __restrict__ XE, const float* __restrict__ XAraw,
    const double* __restrict__ SA2, double invRa,
    const float* __restrict__ Wf1, float* __restrict__ F1, double* __restrict__ Sf1)
{
    __shared__ float wlds[4096];
    __shared__ float v[4][2][64];
    __shared__ float ssa[64];
    __shared__ double red[256];
    int tid = threadIdx.x;
    for (int i = tid; i < 4096; i += 256) wlds[i] = Wf1[i];
    if (tid < 64) ssa[tid] = qbn_s(SA2, tid, invRa);
    __syncthreads();
    int grp = tid>>6, ch = tid&63;
    int agent = blockIdx.x*4 + grp;
    float best = -1.f, v0 = 0.f, v1 = 0.f;
    for (int e = 0; e < NEN; ++e) {
        size_t b = (size_t)(agent*NEN+e)*128;
        float x0 = XE[b+ch], x1 = XE[b+64+ch];
        float m2 = pair_m2(x0,x1);
        if (m2 > best) { best = m2; v0 = x0; v1 = x1; }
    }
    float sa = ssa[ch];
    for (int l = 0; l < NALY; ++l) {
        size_t b = (size_t)(agent*NALY+l)*128;
        float r0 = XAraw[b+ch], r1 = XAraw[b+64+ch];
        float u0 = r0/sa, u1 = r1/sa;
        float modf = sqrtf(pair_m2(u0,u1));
        float cff = modf / fmaxf(1.f, modf);
        float x0 = __fmul_rn(u0,cff), x1 = __fmul_rn(u1,cff);
        float m2 = pair_m2(x0,x1);
        if (m2 > best) { best = m2; v0 = x0; v1 = x1; }
    }
    v[grp][0][ch] = v0; v[grp][1][ch] = v1;
    __syncthreads();
    float a0 = 0.f, a1 = 0.f;
#pragma unroll
    for (int k = 0; k < 64; ++k) {
        float w = wlds[k*64+ch];
        a0 = fmaf(v[grp][0][k], w, a0);
        a1 = fmaf(v[grp][1][k], w, a1);
    }
    F1[(size_t)agent*128+ch] = a0; F1[(size_t)agent*128+64+ch] = a1;
    red[tid] = (double)a0*a0 + (double)a1*a1;
    __syncthreads();
    red_to_S(red, Sf1, blockIdx.x, tid);
}

// ---- vf finalize + SFb + VT = vf @ W1top for both imp chains. ----
__global__ __launch_bounds__(256) void k_vf_vtop(
    const float* __restrict__ F1, const double* __restrict__ Sf2,
    float* __restrict__ SFb,
    const float* __restrict__ Wie1, const float* __restrict__ Wia1,
    float* __restrict__ VTie, float* __restrict__ VTia, double invRows)
{
    __shared__ float wie[4096];
    __shared__ float wia[4096];
    __shared__ float vf[4][2][64];
    int tid = threadIdx.x;
    for (int i = tid; i < 4096; i += 256) { wie[i] = Wie1[i]; wia[i] = Wia1[i]; }
    int grp = tid>>6, ch = tid&63;
    int agent = blockIdx.x*4 + grp;
    float x0 = F1[(size_t)agent*128+ch], x1 = F1[(size_t)agent*128+64+ch];
    float s = qbn_s(Sf2, ch, invRows);
    float u0 = x0/s, u1 = x1/s;
    float mod = sqrtf(pair_m2(u0,u1));
    float cf = mod / fmaxf(1.f, mod);
    float y0 = __fmul_rn(u0,cf), y1 = __fmul_rn(u1,cf);
    vf[grp][0][ch] = y0; vf[grp][1][ch] = y1;
    SFb[(size_t)agent*64+ch] = pair_m2(y0,y1);
    __syncthreads();
    float a0=0.f,a1=0.f,b0=0.f,b1=0.f;
#pragma unroll
    for (int k = 0; k < 64; ++k) {
        float f0 = vf[grp][0][k], f1 = vf[grp][1][k];
        a0 = fmaf(f0, wie[k*64+ch], a0); a1 = fmaf(f1, wie[k*64+ch], a1);
        b0 = fmaf(f0, wia[k*64+ch], b0); b1 = fmaf(f1, wia[k*64+ch], b1);
    }
    VTie[(size_t)agent*128+ch] = a0; VTie[(size_t)agent*128+64+ch] = a1;
    VTia[(size_t)agent*128+ch] = b0; VTia[(size_t)agent*128+64+ch] = b1;
}

// ---- imp layer1: XI = VT + XE @ W1bot; 8 ents/block, ch-vectorized. ----
__global__ __launch_bounds__(256) void k_imp1(
    const float* __restrict__ XE, const float* __restrict__ VT,
    const float* __restrict__ W1, float* __restrict__ XI, double* __restrict__ S1)
{
    __shared__ float wlds[4096];
    __shared__ float xt[16][68];      // 16 rows=(ent,c) x 64 k, padded
    __shared__ double dredw[4][64];
    int tid = threadIdx.x;
    for (int i = tid; i < 4096; i += 256) wlds[i] = W1[4096 + i];
    {
        int r = tid >> 4;             // 256 float4 = 16 rows x 16 quads
        int kq = (tid & 15) * 4;
        float4 t4 = *(const float4*)&XE[(size_t)blockIdx.x*1024 + tid*4];
        *(float4*)&xt[r][kq] = t4;
    }
    __syncthreads();
    int rl = tid >> 4;
    int ch0 = (tid & 15) * 4;
    int ent = blockIdx.x*8 + (rl >> 1);
    int c = rl & 1;
    int agent = ent / NEN;
    float4 vt = *(const float4*)&VT[(size_t)agent*128 + c*64 + ch0];
    float acc[4] = {vt.x, vt.y, vt.z, vt.w};
#pragma unroll
    for (int k = 0; k < 64; k += 4) {
        float4 x4 = *(const float4*)&xt[rl][k];
        float xk[4] = {x4.x, x4.y, x4.z, x4.w};
#pragma unroll
        for (int kk = 0; kk < 4; ++kk) {
            float4 w4 = *(const float4*)&wlds[(k+kk)*64 + ch0];
            acc[0] = fmaf(xk[kk], w4.x, acc[0]);
            acc[1] = fmaf(xk[kk], w4.y, acc[1]);
            acc[2] = fmaf(xk[kk], w4.z, acc[2]);
            acc[3] = fmaf(xk[kk], w4.w, acc[3]);
        }
    }
    *(float4*)&XI[(size_t)ent*128 + c*64 + ch0] = make_float4(acc[0],acc[1],acc[2],acc[3]);
    {
        int wv = tid >> 6;
#pragma unroll
        for (int i = 0; i < 4; ++i) {
            double d = (double)acc[i]*acc[i];
            d += __shfl_xor(d, 16, 64);
            d += __shfl_xor(d, 32, 64);
            if ((tid & 48) == 0) dredw[wv][ch0+i] = d;
        }
    }
    __syncthreads();
    if (tid < 64) {
        double v = dredw[0][tid] + dredw[1][tid] + dredw[2][tid] + dredw[3][tid];
        atomicAdd(&S1[(blockIdx.x & 15)*64 + tid], v);
    }
}

// ---- imp layer3: 16 ents/block; one strided atomic per block. ----
__global__ __launch_bounds__(256) void k_imp3(
    const float* __restrict__ XI, const double* __restrict__ S2,
    const float* __restrict__ W3, float* __restrict__ Z, double* __restrict__ S3,
    double invRows)
{
    __shared__ float ss[64];
    __shared__ double red4[4];
    int tid = threadIdx.x; int grp = tid>>6, ch = tid&63;
    if (tid < 64) ss[tid] = qbn_s(S2, tid, invRows);
    __syncthreads();
    float s = ss[ch];
    double w3 = (double)W3[ch];
    double lr3 = 0.0;
#pragma unroll
    for (int i = 0; i < 4; ++i) {
        int ent = blockIdx.x*16 + grp + 4*i;
        float x0 = XI[(size_t)ent*128+ch], x1 = XI[(size_t)ent*128+64+ch];
        float u0 = x0/s, u1 = x1/s;
        float mod = sqrtf(pair_m2(u0,u1));
        float cf = mod / fmaxf(1.f, mod);
        double v0 = (double)__fmul_rn(u0,cf) * w3;
        double v1 = (double)__fmul_rn(u1,cf) * w3;
#pragma unroll
        for (int m = 1; m < 64; m <<= 1) { v0 += __shfl_xor(v0,m,64); v1 += __shfl_xor(v1,m,64); }
        if (ch == 0) {
            float z0 = (float)v0, z1 = (float)v1;
            Z[(size_t)ent*2] = z0; Z[(size_t)ent*2+1] = z1;
            lr3 += (double)z0*z0 + (double)z1*z1;
        }
    }
    if (ch == 0) red4[grp] = lr3;
    __syncthreads();
    if (tid == 0) atomicAdd(&S3[(blockIdx.x & 15)*8], red4[0]+red4[1]+red4[2]+red4[3]);
}

// ---- move_vec + oaq head + output cols 0..5. ----
__global__ __launch_bounds__(256) void k_final_small(
    const float* __restrict__ Zie, const float* __restrict__ Zia,
    const double* __restrict__ Sie3, const double* __restrict__ Sia3,
    const float* __restrict__ SFb,
    const float* __restrict__ Woa1, const float* __restrict__ boa1,
    const float* __restrict__ Woa2, const float* __restrict__ boa2,
    float* __restrict__ out, double invRows)
{
    __shared__ float sflds[4][64];
    int tid = threadIdx.x; int grp = tid>>6, ch = tid&63;
    int agent = blockIdx.x*4 + grp;
    float sie = sqrtf((float)(sum16sd8(Sie3)*invRows) + EPSF);
    float sia = sqrtf((float)(sum16sd8(Sia3)*invRows) + EPSF);
    double pv0 = 0.0, pv1 = 0.0;
    if (ch < NEN) {
        int ent = agent*NEN + ch;
        float z0 = Zie[(size_t)ent*2]/sie, z1 = Zie[(size_t)ent*2+1]/sie;
        float mod = sqrtf(pair_m2(z0,z1)); float cf = mod/fmaxf(1.f,mod);
        pv0 = (double)__fmul_rn(z0,cf); pv1 = (double)__fmul_rn(z1,cf);
        z0 = Zia[(size_t)ent*2]/sia; z1 = Zia[(size_t)ent*2+1]/sia;
        mod = sqrtf(pair_m2(z0,z1)); cf = mod/fmaxf(1.f,mod);
        pv0 += (double)__fmul_rn(z0,cf); pv1 += (double)__fmul_rn(z1,cf);
    }
#pragma unroll
    for (int m = 1; m < 64; m <<= 1) { pv0 += __shfl_xor(pv0,m,64); pv1 += __shfl_xor(pv1,m,64); }
    sflds[grp][ch] = SFb[(size_t)agent*64+ch];
    __syncthreads();
    double hd = (double)boa1[ch];
#pragma unroll
    for (int k = 0; k < 64; ++k) hd += (double)sflds[grp][k]*(double)Woa1[k*64+ch];
    float h = fmaxf((float)hd, 0.f);
    double q0 = (double)h*(double)Woa2[ch*3+0];
    double q1 = (double)h*(double)Woa2[ch*3+1];
    double q2 = (double)h*(double)Woa2[ch*3+2];
#pragma unroll
    for (int m = 1; m < 64; m <<= 1) { q0 += __shfl_xor(q0,m,64); q1 += __shfl_xor(q1,m,64); q2 += __shfl_xor(q2,m,64); }
    if (ch == 0) {
        float oaq0 = (float)(q0 + (double)boa2[0]);
        float oaq1 = (float)(q1 + (double)boa2[1]);
        float mmq  = (float)(q2 + (double)boa2[2]);
        float mv0 = (float)pv0, mv1 = (float)pv1;
        float* o = out + (size_t)agent*16;
        o[0] = oaq0; o[1] = oaq1;
        o[2] = mmq + mv1; o[3] = mmq - mv1;
        o[4] = mmq + mv0; o[5] = mmq - mv0;
    }
}

// ---- Attention MLP (128->128->64->1), f32, 16 rows/block.
//      R12's proven indexing (scalar coalesced W, broadcast rows) with
//      TRANSPOSED LDS tiles: 8-row read at fixed k = 2 ds_read_b128. ----
__global__ __launch_bounds__(256) void k_attn(
    const float* __restrict__ SFb, const float* __restrict__ XE,
    const float* __restrict__ W1, const float* __restrict__ b1,
    const float* __restrict__ W2, const float* __restrict__ b2,
    const float* __restrict__ W3, const float* __restrict__ b3,
    float* __restrict__ out)
{
    __shared__ float atfT[128][20];   // [k][row], padded to 20
    __shared__ float h1T[128][20];    // [k][row]
    __shared__ float h2[16][68];
    int tid = threadIdx.x;
    int row0 = blockIdx.x*16;
#pragma unroll
    for (int i = 0; i < 8; ++i) {
        int idx = tid + i*256; int r = idx>>7; int j = idx&127;
        int ent = row0 + r; int agent = ent/NEN;
        float v;
        if (j < 64) v = SFb[(size_t)agent*64+j];
        else {
            float x0 = XE[(size_t)ent*128 + (j-64)];
            float x1 = XE[(size_t)ent*128 + 64 + (j-64)];
            v = pair_m2(x0,x1);
        }
        atfT[j][r] = v;
    }
    __syncthreads();
    {   // layer1: j = tid&127 (coalesced W1), rr = tid>>7 -> rows rr*8..+7
        int j = tid & 127, rr = tid >> 7;
        float bb = b1[j];
        float acc[8];
#pragma unroll
        for (int r = 0; r < 8; ++r) acc[r] = bb;
#pragma unroll 4
        for (int k = 0; k < 128; ++k) {
            float w = W1[k*128 + j];
            float4 a0 = *(const float4*)&atfT[k][rr*8];
            float4 a1 = *(const float4*)&atfT[k][rr*8 + 4];
            acc[0] = fmaf(a0.x, w, acc[0]);
            acc[1] = fmaf(a0.y, w, acc[1]);
            acc[2] = fmaf(a0.z, w, acc[2]);
            acc[3] = fmaf(a0.w, w, acc[3]);
            acc[4] = fmaf(a1.x, w, acc[4]);
            acc[5] = fmaf(a1.y, w, acc[5]);
            acc[6] = fmaf(a1.z, w, acc[6]);
            acc[7] = fmaf(a1.w, w, acc[7]);
        }
        float4 o0 = make_float4(fmaxf(acc[0],0.f), fmaxf(acc[1],0.f),
                                fmaxf(acc[2],0.f), fmaxf(acc[3],0.f));
        float4 o1 = make_float4(fmaxf(acc[4],0.f), fmaxf(acc[5],0.f),
                                fmaxf(acc[6],0.f), fmaxf(acc[7],0.f));
        *(float4*)&h1T[j][rr*8]     = o0;
        *(float4*)&h1T[j][rr*8 + 4] = o1;
    }
    __syncthreads();
    {   // layer2: j2 = tid&63 (coalesced W2), rr2 = tid>>6 -> rows rr2*4..+3
        int j2 = tid & 63, rr2 = tid >> 6;
        float bb = b2[j2];
        float acc[4] = {bb, bb, bb, bb};
#pragma unroll 4
        for (int k = 0; k < 128; ++k) {
            float w = W2[k*64 + j2];
            float4 p = *(const float4*)&h1T[k][rr2*4];
            acc[0] = fmaf(p.x, w, acc[0]);
            acc[1] = fmaf(p.y, w, acc[1]);
            acc[2] = fmaf(p.z, w, acc[2]);
            acc[3] = fmaf(p.w, w, acc[3]);
        }
#pragma unroll
        for (int r = 0; r < 4; ++r) h2[rr2*4+r][j2] = fmaxf(acc[r], 0.f);
    }
    __syncthreads();
    {   // layer3: 16 rows, 16 lanes/row
        int r3 = tid >> 4, l3 = tid & 15;
        float s = 0.f;
#pragma unroll
        for (int q = 0; q < 4; ++q) s = fmaf(h2[r3][l3 + 16*q], W3[l3 + 16*q], s);
#pragma unroll
        for (int m = 1; m < 16; m <<= 1) s += __shfl_xor(s, m, 64);
        if (l3 == 0) {
            int ent = row0 + r3; int agent = ent/NEN; int e = ent%NEN;
            out[(size_t)agent*16 + 6 + e] = s + b3[0];
        }
    }
}

extern "C" void kernel_launch(void* const* d_in, const int* in_sizes, int n_in,
                              void* d_out, int out_size, void* d_ws, size_t ws_size,
                              hipStream_t stream) {
    const float* own  = (const float*)d_in[0];
    const float* ef   = (const float*)d_in[1];
    const float* af   = (const float*)d_in[2];
    const float* W_e1 = (const float*)d_in[3];
    const float* W_e2 = (const float*)d_in[4];
    const float* W_a1 = (const float*)d_in[5];
    const float* W_a2 = (const float*)d_in[6];
    const float* W_f1 = (const float*)d_in[7];
    const float* W_f2 = (const float*)d_in[8];
    const float* W_ie1= (const float*)d_in[9];
    const float* W_ie2= (const float*)d_in[10];
    const float* W_ie3= (const float*)d_in[11];
    const float* W_ia1= (const float*)d_in[12];
    const float* W_ia2= (const float*)d_in[13];
    const float* W_ia3= (const float*)d_in[14];
    const float* W_oa1= (const float*)d_in[15];
    const float* b_oa1= (const float*)d_in[16];
    const float* W_oa2= (const float*)d_in[17];
    const float* b_oa2= (const float*)d_in[18];
    const float* W_at1= (const float*)d_in[19];
    const float* b_at1= (const float*)d_in[20];
    const float* W_at2= (const float*)d_in[21];
    const float* b_at2= (const float*)d_in[22];
    const float* W_at3= (const float*)d_in[23];
    const float* b_at3= (const float*)d_in[24];
    float* out = (float*)d_out;
    float* wsf = (float*)d_ws;
    double* Sd = (double*)d_ws;

    size_t o = (size_t)NDOUBLES*2;
    float*  X_E  = wsf + o; o += (size_t)NEE*128;
    float*  X_A  = wsf + o; o += (size_t)NAE*128;
    float*  F1   = wsf + o; o += (size_t)NAG*128;
    float*  SFb  = wsf + o; o += (size_t)NAG*64;
    float*  VT_IE = wsf + o; o += (size_t)NAG*128;
    float*  VT_IA = wsf + o; o += (size_t)NAG*128;
    float*  XI   = wsf + o; o += (size_t)NEE*128;
    float*  Z_IE = wsf + o; o += (size_t)NEE*2;
    float*  Z_IA = wsf + o; o += (size_t)NEE*2;

    double* S_E1 = Sd + DOFF_SE1;  double* S_E2 = Sd + DOFF_SE2;
    double* S_A1 = Sd + DOFF_SA1;  double* S_A2 = Sd + DOFF_SA2;
    double* S_F1 = Sd + DOFF_SF1;  double* S_F2 = Sd + DOFF_SF2;
    double* S_IE1= Sd + DOFF_SIE1; double* S_IE2= Sd + DOFF_SIE2;
    double* S_IA1= Sd + DOFF_SIA1; double* S_IA2= Sd + DOFF_SIA2;
    double* S_IE3= Sd + DOFF_SIE3; double* S_IA3= Sd + DOFF_SIA3;

    const double invRe = 1.0/(double)(NEE*2);
    const double invRa = 1.0/(double)(NAE*2);
    const double invRf = 1.0/(double)(NAG*2);

    hipMemsetAsync(Sd, 0, (size_t)NDOUBLES*sizeof(double), stream);

    k_build_pair<<<NEE/8, 256, 0, stream>>>(ef, own, W_e1, X_E, S_E1, NEN);
    k_build_pair<<<NAE/8, 256, 0, stream>>>(af, own, W_a1, X_A, S_A1, NALY);
    k_pair_layer<<<NEE/16, 256, 0, stream>>>(X_E, S_E1, S_E2, W_e2, invRe);
    k_pair_layer<<<NAE/16, 256, 0, stream>>>(X_A, S_A1, S_A2, W_a2, invRa);
    k_finalize_pair<<<NEE*32/256, 256, 0, stream>>>(X_E, S_E2, invRe);
    k_pool_f1<<<NAG/4, 256, 0, stream>>>(X_E, X_A, S_A2, invRa, W_f1, F1, S_F1);
    k_pair_layer<<<NAG/16, 256, 0, stream>>>(F1, S_F1, S_F2, W_f2, invRf);
    k_vf_vtop<<<NAG/4, 256, 0, stream>>>(F1, S_F2, SFb, W_ie1, W_ia1, VT_IE, VT_IA, invRf);
    // e-importance chain
    k_imp1<<<NEE/8, 256, 0, stream>>>(X_E, VT_IE, W_ie1, XI, S_IE1);
    k_pair_layer<<<NEE/16, 256, 0, stream>>>(XI, S_IE1, S_IE2, W_ie2, invRe);
    k_imp3<<<NEE/16, 256, 0, stream>>>(XI, S_IE2, W_ie3, Z_IE, S_IE3, invRe);
    // a-importance chain (same cat input; XI reused)
    k_imp1<<<NEE/8, 256, 0, stream>>>(X_E, VT_IA, W_ia1, XI, S_IA1);
    k_pair_layer<<<NEE/16, 256, 0, stream>>>(XI, S_IA1, S_IA2, W_ia2, invRe);
    k_imp3<<<NEE/16, 256, 0, stream>>>(XI, S_IA2, W_ia3, Z_IA, S_IA3, invRe);

    k_final_small<<<NAG/4, 256, 0, stream>>>(Z_IE, Z_IA, S_IE3, S_IA3, SFb,
                                             W_oa1, b_oa1, W_oa2, b_oa2, out, invRe);
    k_attn<<<NEE/16, 256, 0, stream>>>(SFb, X_E, W_at1, b_at1, W_at2, b_at2,
                                       W_at3, b_at3, out);
}

// Round 16
// 665.677 us; speedup vs baseline: 1.1642x; 1.0380x over previous
//
#include <hip/hip_runtime.h>
#include <math.h>

// Problem constants
#define BATCH 1024
#define NA 10
#define NEN 10
#define NALY 9
#define NAG (BATCH*NA)          // 10240
#define NEE (NAG*NEN)           // 102400
#define NAE (NAG*NALY)          // 92160
#define EPSF 1e-5f

// f64 replicated qbn-sum buffers (16 replicas), at start of ws (double units)
#define DOFF_SE1 0
#define DOFF_SE2 1024
#define DOFF_SA1 2048
#define DOFF_SA2 3072
#define DOFF_SF1 4096
#define DOFF_SF2 5120
#define DOFF_SIE1 6144
#define DOFF_SIE2 7168
#define DOFF_SIA1 8192
#define DOFF_SIA2 9216
#define DOFF_SIE3 10240   // 16 replicas x stride 8
#define DOFF_SIA3 10368
#define NDOUBLES 16384

#define NBLK_BE (NEE/8)   // 12800
#define NBLK_BA (NAE/8)   // 11520
#define NBLK_PE (NEE/16)  // 6400
#define NBLK_PA (NAE/16)  // 5760

__device__ __forceinline__ double sum16vd(const double* __restrict__ S, int ch) {
    double s = 0.0;
#pragma unroll
    for (int r = 0; r < 16; ++r) s += S[r*64 + ch];
    return s;
}
__device__ __forceinline__ double sum16sd8(const double* __restrict__ S) {
    double s = 0.0;
#pragma unroll
    for (int r = 0; r < 16; ++r) s += S[r*8];
    return s;
}
__device__ __forceinline__ float qbn_s(const double* __restrict__ S, int ch, double invRows) {
    float m = (float)(sum16vd(S, ch)*invRows);
    return sqrtf(m + EPSF);
}
__device__ __forceinline__ void red_to_S(const double* red, double* S, int bid, int tid) {
    if (tid < 64) {
        double v = red[tid] + red[tid+64] + red[tid+128] + red[tid+192];
        atomicAdd(&S[(bid & 15)*64 + tid], v);
    }
}
// np-lattice pair mod^2: fl(fl(x0^2)+fl(x1^2)) (no FMA contraction)
__device__ __forceinline__ float pair_m2(float x0, float x1) {
    return __fadd_rn(__fmul_rn(x0,x0), __fmul_rn(x1,x1));
}

// ---- build_vec + layer1 GEMM, E and A fused in one launch.
//      Per-output FP sequence identical to R10 (REVERSED k, FROZEN). ----
__global__ __launch_bounds__(256) void k_build_both(
    const float* __restrict__ ef, const float* __restrict__ af,
    const float* __restrict__ own,
    const float* __restrict__ We1, const float* __restrict__ Wa1,
    float* __restrict__ XE, float* __restrict__ XA,
    double* __restrict__ SE1, double* __restrict__ SA1)
{
    bool isA = (blockIdx.x >= NBLK_BE);
    int blk = isA ? (blockIdx.x - NBLK_BE) : blockIdx.x;
    const float* feats = isA ? af : ef;
    const float* W1    = isA ? Wa1 : We1;
    float* X           = isA ? XA : XE;
    double* S1         = isA ? SA1 : SE1;
    int nEntPerAgent   = isA ? NALY : NEN;

    __shared__ float wlds[19*64];
    __shared__ float g[8][19];
    __shared__ float pxy[8][2];
    __shared__ double red[256];
    int tid = threadIdx.x;
    for (int i = tid; i < 19*64; i += 256) wlds[i] = W1[i];
    if (tid < 152) {
        int el = tid / 19, chg = tid % 19;
        int ent = blk*8 + el;
        const float* f = feats + (size_t)ent*9;
        int agent = ent / nEntPerAgent;
        float px = f[2], py = f[3];
        float pm = sqrtf(__fadd_rn(__fmul_rn(px,px), __fmul_rn(py,py)));
        float val;
        if (chg == 0) val = 1.f;
        else if (chg < 8) {
            int j = chg - 1;
            int fi = (j < 2) ? j : (j + 2);
            float o = f[fi];
            float om = sqrtf(__fmul_rn(__fmul_rn(2.0f,o),o));
            val = (pm == 0.f) ? 0.f : __fdiv_rn(om, pm);
        } else {
            float o = own[(size_t)agent*11 + (chg-8)];
            float t = __fmul_rn(o,o);
            float om = sqrtf(__fadd_rn(t,t));
            val = (pm == 0.f) ? 0.f : __fdiv_rn(om, pm);
        }
        g[el][chg] = val;
        if (chg == 0) { pxy[el][0] = px; pxy[el][1] = py; }
    }
    __syncthreads();
    int l = tid >> 7, c = (tid >> 6) & 1, ch = tid & 63;
    double lr = 0.0;
#pragma unroll
    for (int i = 0; i < 4; ++i) {
        int el = l + 2*i;
        int ent = blk*8 + el;
        float pc = pxy[el][c];
        float acc = 0.f;
#pragma unroll
        for (int k = 18; k >= 0; --k) {            // REVERSED k (frozen)
            float ev = __fmul_rn(pc, g[el][k]);
            acc = fmaf(ev, wlds[k*64+ch], acc);
        }
        X[(size_t)ent*128 + c*64 + ch] = acc;
        lr += (double)acc * (double)acc;
    }
    red[tid] = lr;
    __syncthreads();
    red_to_S(red, S1, blk, tid);
}

// ---- pair-layer core (shared by fused and generic kernels). ----
__device__ __forceinline__ void pair_layer_body(
    float* __restrict__ X, const double* __restrict__ Sin, double* __restrict__ Sout,
    const float* __restrict__ W, double invRows, int blk)
{
    __shared__ float wlds[4096];
    __shared__ float ybuf[16][132];
    __shared__ float ss[64];
    __shared__ double dredw[4][64];
    int tid = threadIdx.x;
    for (int i = tid; i < 4096; i += 256) wlds[i] = W[i];
    if (tid < 64) ss[tid] = qbn_s(Sin, tid, invRows);
    __syncthreads();
    int rl = tid >> 4;
    int ch0 = (tid & 15) * 4;
    size_t row = (size_t)blk*16 + rl;
    float4 xv0 = *(const float4*)&X[row*128 + ch0];
    float4 xv1 = *(const float4*)&X[row*128 + 64 + ch0];
    {
        float xs0[4] = {xv0.x,xv0.y,xv0.z,xv0.w};
        float xs1[4] = {xv1.x,xv1.y,xv1.z,xv1.w};
        float y0[4], y1[4];
#pragma unroll
        for (int i = 0; i < 4; ++i) {
            float s = ss[ch0+i];
            float u0 = xs0[i]/s, u1 = xs1[i]/s;
            float mod = sqrtf(pair_m2(u0,u1));
            float cf = mod / fmaxf(1.f, mod);
            y0[i] = __fmul_rn(u0,cf);
            y1[i] = __fmul_rn(u1,cf);
        }
        *(float4*)&ybuf[rl][2*ch0]     = make_float4(y0[0],y1[0],y0[1],y1[1]);
        *(float4*)&ybuf[rl][2*ch0 + 4] = make_float4(y0[2],y1[2],y0[3],y1[3]);
    }
    __syncthreads();
    float a0[4] = {0.f,0.f,0.f,0.f};
    float a1[4] = {0.f,0.f,0.f,0.f};
#pragma unroll
    for (int k = 63; k >= 1; k -= 2) {           // REVERSED k (frozen)
        float4 wk  = *(const float4*)&wlds[k*64 + ch0];
        float4 wk1 = *(const float4*)&wlds[(k-1)*64 + ch0];
        float4 y4  = *(const float4*)&ybuf[rl][2*k - 2];
        float wkv[4]  = {wk.x,wk.y,wk.z,wk.w};
        float wk1v[4] = {wk1.x,wk1.y,wk1.z,wk1.w};
#pragma unroll
        for (int i = 0; i < 4; ++i) {
            a0[i] = fmaf(y4.z, wkv[i], a0[i]);
            a1[i] = fmaf(y4.w, wkv[i], a1[i]);
        }
#pragma unroll
        for (int i = 0; i < 4; ++i) {
            a0[i] = fmaf(y4.x, wk1v[i], a0[i]);
            a1[i] = fmaf(y4.y, wk1v[i], a1[i]);
        }
    }
    *(float4*)&X[row*128 + ch0]      = make_float4(a0[0],a0[1],a0[2],a0[3]);
    *(float4*)&X[row*128 + 64 + ch0] = make_float4(a1[0],a1[1],a1[2],a1[3]);
    {
        int wv = tid >> 6;
#pragma unroll
        for (int i = 0; i < 4; ++i) {
            double d = (double)a0[i]*a0[i] + (double)a1[i]*a1[i];
            d += __shfl_xor(d, 16, 64);
            d += __shfl_xor(d, 32, 64);
            if ((tid & 48) == 0) dredw[wv][ch0+i] = d;
        }
    }
    __syncthreads();
    if (tid < 64) {
        double v = dredw[0][tid] + dredw[1][tid] + dredw[2][tid] + dredw[3][tid];
        atomicAdd(&Sout[(blk & 15)*64 + tid], v);
    }
}

// ---- first pair layer, E and A fused in one launch. ----
__global__ __launch_bounds__(256) void k_pair_both(
    float* __restrict__ XE, const double* __restrict__ SE1, double* __restrict__ SE2,
    const float* __restrict__ We2, double invRe,
    float* __restrict__ XA, const double* __restrict__ SA1, double* __restrict__ SA2,
    const float* __restrict__ Wa2, double invRa)
{
    if (blockIdx.x < NBLK_PE)
        pair_layer_body(XE, SE1, SE2, We2, invRe, blockIdx.x);
    else
        pair_layer_body(XA, SA1, SA2, Wa2, invRa, blockIdx.x - NBLK_PE);
}

// ---- generic pair layer (F1 and imp chains). ----
__global__ __launch_bounds__(256) void k_pair_layer(
    float* __restrict__ X, const double* __restrict__ Sin, double* __restrict__ Sout,
    const float* __restrict__ W, double invRows)
{
    pair_layer_body(X, Sin, Sout, W, invRows, blockIdx.x);
}

// ---- Finalize (E only): y = qrelu(qbn(x)) in place + ESC = pair_m2. ----
__global__ __launch_bounds__(256) void k_finalize_pair(
    float* __restrict__ X, const double* __restrict__ S2, double invRows,
    float* __restrict__ ESC)
{
    __shared__ float ss[64];
    if (threadIdx.x < 64) ss[threadIdx.x] = qbn_s(S2, threadIdx.x, invRows);
    int t = blockIdx.x*256 + threadIdx.x;
    int rl = t >> 4;              // (ent*2 + c) row index
    int ch0 = (t & 15) * 4;
    size_t base    = (size_t)rl*64 + ch0;
    size_t partner = (size_t)(rl ^ 1)*64 + ch0;
    float4 xv  = *(const float4*)&X[base];
    float4 xov = *(const float4*)&X[partner];
    __syncthreads();
    float xs[4]  = {xv.x,xv.y,xv.z,xv.w};
    float xos[4] = {xov.x,xov.y,xov.z,xov.w};
    float r[4], esc[4];
    int c = rl & 1;
#pragma unroll
    for (int i = 0; i < 4; ++i) {
        float s = ss[ch0+i];
        float u  = xs[i]/s;
        float uo = xos[i]/s;
        float u0 = (c==0) ? u : uo, u1 = (c==0) ? uo : u;
        float mod = sqrtf(pair_m2(u0,u1));
        float cf = mod / fmaxf(1.f, mod);
        r[i] = __fmul_rn(u, cf);
        if (c == 0) {
            float y1v = __fmul_rn(uo, cf);   // identical bits to partner's write
            esc[i] = pair_m2(r[i], y1v);
        }
    }
    *(float4*)&X[base] = make_float4(r[0],r[1],r[2],r[3]);
    if (c == 0) {
        int ent = rl >> 1;
        *(float4*)&ESC[(size_t)ent*64 + ch0] = make_float4(esc[0],esc[1],esc[2],esc[3]);
    }
}

// ---- Pool + f1 GEMM, ally finalize fused (identical op sequence). ----
__global__ __launch_bounds__(256) void k_pool_f1(
    const float* __restrict__ XE, const float* __restrict__ XAraw,
    const double* __restrict__ SA2, double invRa,
    const float* __restrict__ Wf1, float* __restrict__ F1, double* __restrict__ Sf1)
{
    __shared__ float wlds[4096];
    __shared__ float v[4][2][64];
    __shared__ float ssa[64];
    __shared__ double red[256];
    int tid = threadIdx.x;
    for (int i = tid; i < 4096; i += 256) wlds[i] = Wf1[i];
    if (tid < 64) ssa[tid] = qbn_s(SA2, tid, invRa);
    __syncthreads();
    int grp = tid>>6, ch = tid&63;
    int agent = blockIdx.x*4 + grp;
    float best = -1.f, v0 = 0.f, v1 = 0.f;
    for (int e = 0; e < NEN; ++e) {
        size_t b = (size_t)(agent*NEN+e)*128;
        float x0 = XE[b+ch], x1 = XE[b+64+ch];
        float m2 = pair_m2(x0,x1);
        if (m2 > best) { best = m2; v0 = x0; v1 = x1; }
    }
    float sa = ssa[ch];
    for (int l = 0; l < NALY; ++l) {
        size_t b = (size_t)(agent*NALY+l)*128;
        float r0 = XAraw[b+ch], r1 = XAraw[b+64+ch];
        float u0 = r0/sa, u1 = r1/sa;
        float modf = sqrtf(pair_m2(u0,u1));
        float cff = modf / fmaxf(1.f, modf);
        float x0 = __fmul_rn(u0,cff), x1 = __fmul_rn(u1,cff);
        float m2 = pair_m2(x0,x1);
        if (m2 > best) { best = m2; v0 = x0; v1 = x1; }
    }
    v[grp][0][ch] = v0; v[grp][1][ch] = v1;
    __syncthreads();
    float a0 = 0.f, a1 = 0.f;
#pragma unroll
    for (int k = 0; k < 64; ++k) {
        float w = wlds[k*64+ch];
        a0 = fmaf(v[grp][0][k], w, a0);
        a1 = fmaf(v[grp][1][k], w, a1);
    }
    F1[(size_t)agent*128+ch] = a0; F1[(size_t)agent*128+64+ch] = a1;
    red[tid] = (double)a0*a0 + (double)a1*a1;
    __syncthreads();
    red_to_S(red, Sf1, blockIdx.x, tid);
}

// ---- vf finalize + SFb + VT = vf @ W1top for both imp chains. ----
__global__ __launch_bounds__(256) void k_vf_vtop(
    const float* __restrict__ F1, const double* __restrict__ Sf2,
    float* __restrict__ SFb,
    const float* __restrict__ Wie1, const float* __restrict__ Wia1,
    float* __restrict__ VTie, float* __restrict__ VTia, double invRows)
{
    __shared__ float wie[4096];
    __shared__ float wia[4096];
    __shared__ float vf[4][2][64];
    int tid = threadIdx.x;
    for (int i = tid; i < 4096; i += 256) { wie[i] = Wie1[i]; wia[i] = Wia1[i]; }
    int grp = tid>>6, ch = tid&63;
    int agent = blockIdx.x*4 + grp;
    float x0 = F1[(size_t)agent*128+ch], x1 = F1[(size_t)agent*128+64+ch];
    float s = qbn_s(Sf2, ch, invRows);
    float u0 = x0/s, u1 = x1/s;
    float mod = sqrtf(pair_m2(u0,u1));
    float cf = mod / fmaxf(1.f, mod);
    float y0 = __fmul_rn(u0,cf), y1 = __fmul_rn(u1,cf);
    vf[grp][0][ch] = y0; vf[grp][1][ch] = y1;
    SFb[(size_t)agent*64+ch] = pair_m2(y0,y1);
    __syncthreads();
    float a0=0.f,a1=0.f,b0=0.f,b1=0.f;
#pragma unroll
    for (int k = 0; k < 64; ++k) {
        float f0 = vf[grp][0][k], f1 = vf[grp][1][k];
        a0 = fmaf(f0, wie[k*64+ch], a0); a1 = fmaf(f1, wie[k*64+ch], a1);
        b0 = fmaf(f0, wia[k*64+ch], b0); b1 = fmaf(f1, wia[k*64+ch], b1);
    }
    VTie[(size_t)agent*128+ch] = a0; VTie[(size_t)agent*128+64+ch] = a1;
    VTia[(size_t)agent*128+ch] = b0; VTia[(size_t)agent*128+64+ch] = b1;
}

// ---- imp layer1: XI = VT + XE @ W1bot; 8 ents/block, ch-vectorized. ----
__global__ __launch_bounds__(256) void k_imp1(
    const float* __restrict__ XE, const float* __restrict__ VT,
    const float* __restrict__ W1, float* __restrict__ XI, double* __restrict__ S1)
{
    __shared__ float wlds[4096];
    __shared__ float xt[16][68];
    __shared__ double dredw[4][64];
    int tid = threadIdx.x;
    for (int i = tid; i < 4096; i += 256) wlds[i] = W1[4096 + i];
    {
        int r = tid >> 4;
        int kq = (tid & 15) * 4;
        float4 t4 = *(const float4*)&XE[(size_t)blockIdx.x*1024 + tid*4];
        *(float4*)&xt[r][kq] = t4;
    }
    __syncthreads();
    int rl = tid >> 4;
    int ch0 = (tid & 15) * 4;
    int ent = blockIdx.x*8 + (rl >> 1);
    int c = rl & 1;
    int agent = ent / NEN;
    float4 vt = *(const float4*)&VT[(size_t)agent*128 + c*64 + ch0];
    float acc[4] = {vt.x, vt.y, vt.z, vt.w};
#pragma unroll
    for (int k = 0; k < 64; k += 4) {
        float4 x4 = *(const float4*)&xt[rl][k];
        float xk[4] = {x4.x, x4.y, x4.z, x4.w};
#pragma unroll
        for (int kk = 0; kk < 4; ++kk) {
            float4 w4 = *(const float4*)&wlds[(k+kk)*64 + ch0];
            acc[0] = fmaf(xk[kk], w4.x, acc[0]);
            acc[1] = fmaf(xk[kk], w4.y, acc[1]);
            acc[2] = fmaf(xk[kk], w4.z, acc[2]);
            acc[3] = fmaf(xk[kk], w4.w, acc[3]);
        }
    }
    *(float4*)&XI[(size_t)ent*128 + c*64 + ch0] = make_float4(acc[0],acc[1],acc[2],acc[3]);
    {
        int wv = tid >> 6;
#pragma unroll
        for (int i = 0; i < 4; ++i) {
            double d = (double)acc[i]*acc[i];
            d += __shfl_xor(d, 16, 64);
            d += __shfl_xor(d, 32, 64);
            if ((tid & 48) == 0) dredw[wv][ch0+i] = d;
        }
    }
    __syncthreads();
    if (tid < 64) {
        double v = dredw[0][tid] + dredw[1][tid] + dredw[2][tid] + dredw[3][tid];
        atomicAdd(&S1[(blockIdx.x & 15)*64 + tid], v);
    }
}

// ---- imp layer3: 16 ents/block; one strided atomic per block. ----
__global__ __launch_bounds__(256) void k_imp3(
    const float* __restrict__ XI, const double* __restrict__ S2,
    const float* __restrict__ W3, float* __restrict__ Z, double* __restrict__ S3,
    double invRows)
{
    __shared__ float ss[64];
    __shared__ double red4[4];
    int tid = threadIdx.x; int grp = tid>>6, ch = tid&63;
    if (tid < 64) ss[tid] = qbn_s(S2, tid, invRows);
    __syncthreads();
    float s = ss[ch];
    double w3 = (double)W3[ch];
    double lr3 = 0.0;
#pragma unroll
    for (int i = 0; i < 4; ++i) {
        int ent = blockIdx.x*16 + grp + 4*i;
        float x0 = XI[(size_t)ent*128+ch], x1 = XI[(size_t)ent*128+64+ch];
        float u0 = x0/s, u1 = x1/s;
        float mod = sqrtf(pair_m2(u0,u1));
        float cf = mod / fmaxf(1.f, mod);
        double v0 = (double)__fmul_rn(u0,cf) * w3;
        double v1 = (double)__fmul_rn(u1,cf) * w3;
#pragma unroll
        for (int m = 1; m < 64; m <<= 1) { v0 += __shfl_xor(v0,m,64); v1 += __shfl_xor(v1,m,64); }
        if (ch == 0) {
            float z0 = (float)v0, z1 = (float)v1;
            Z[(size_t)ent*2] = z0; Z[(size_t)ent*2+1] = z1;
            lr3 += (double)z0*z0 + (double)z1*z1;
        }
    }
    if (ch == 0) red4[grp] = lr3;
    __syncthreads();
    if (tid == 0) atomicAdd(&S3[(blockIdx.x & 15)*8], red4[0]+red4[1]+red4[2]+red4[3]);
}

// ---- move_vec + oaq head + output cols 0..5. ----
__global__ __launch_bounds__(256) void k_final_small(
    const float* __restrict__ Zie, const float* __restrict__ Zia,
    const double* __restrict__ Sie3, const double* __restrict__ Sia3,
    const float* __restrict__ SFb,
    const float* __restrict__ Woa1, const float* __restrict__ boa1,
    const float* __restrict__ Woa2, const float* __restrict__ boa2,
    float* __restrict__ out, double invRows)
{
    __shared__ float sflds[4][64];
    int tid = threadIdx.x; int grp = tid>>6, ch = tid&63;
    int agent = blockIdx.x*4 + grp;
    float sie = sqrtf((float)(sum16sd8(Sie3)*invRows) + EPSF);
    float sia = sqrtf((float)(sum16sd8(Sia3)*invRows) + EPSF);
    double pv0 = 0.0, pv1 = 0.0;
    if (ch < NEN) {
        int ent = agent*NEN + ch;
        float z0 = Zie[(size_t)ent*2]/sie, z1 = Zie[(size_t)ent*2+1]/sie;
        float mod = sqrtf(pair_m2(z0,z1)); float cf = mod/fmaxf(1.f,mod);
        pv0 = (double)__fmul_rn(z0,cf); pv1 = (double)__fmul_rn(z1,cf);
        z0 = Zia[(size_t)ent*2]/sia; z1 = Zia[(size_t)ent*2+1]/sia;
        mod = sqrtf(pair_m2(z0,z1)); cf = mod/fmaxf(1.f,mod);
        pv0 += (double)__fmul_rn(z0,cf); pv1 += (double)__fmul_rn(z1,cf);
    }
#pragma unroll
    for (int m = 1; m < 64; m <<= 1) { pv0 += __shfl_xor(pv0,m,64); pv1 += __shfl_xor(pv1,m,64); }
    sflds[grp][ch] = SFb[(size_t)agent*64+ch];
    __syncthreads();
    double hd = (double)boa1[ch];
#pragma unroll
    for (int k = 0; k < 64; ++k) hd += (double)sflds[grp][k]*(double)Woa1[k*64+ch];
    float h = fmaxf((float)hd, 0.f);
    double q0 = (double)h*(double)Woa2[ch*3+0];
    double q1 = (double)h*(double)Woa2[ch*3+1];
    double q2 = (double)h*(double)Woa2[ch*3+2];
#pragma unroll
    for (int m = 1; m < 64; m <<= 1) { q0 += __shfl_xor(q0,m,64); q1 += __shfl_xor(q1,m,64); q2 += __shfl_xor(q2,m,64); }
    if (ch == 0) {
        float oaq0 = (float)(q0 + (double)boa2[0]);
        float oaq1 = (float)(q1 + (double)boa2[1]);
        float mmq  = (float)(q2 + (double)boa2[2]);
        float mv0 = (float)pv0, mv1 = (float)pv1;
        float* o = out + (size_t)agent*16;
        o[0] = oaq0; o[1] = oaq1;
        o[2] = mmq + mv1; o[3] = mmq - mv1;
        o[4] = mmq + mv0; o[5] = mmq - mv0;
    }
}

// ---- Attention MLP (128->128->64->1), f32, 16 rows/block, transposed
//      broadcast tiles + unroll 8 W-load pipelining; reads ESC not XE. ----
__global__ __launch_bounds__(256) void k_attn(
    const float* __restrict__ SFb, const float* __restrict__ ESC,
    const float* __restrict__ W1, const float* __restrict__ b1,
    const float* __restrict__ W2, const float* __restrict__ b2,
    const float* __restrict__ W3, const float* __restrict__ b3,
    float* __restrict__ out)
{
    __shared__ float atfT[128][20];
    __shared__ float h1T[128][20];
    __shared__ float h2[16][68];
    int tid = threadIdx.x;
    int row0 = blockIdx.x*16;
#pragma unroll
    for (int i = 0; i < 8; ++i) {
        int idx = tid + i*256; int r = idx>>7; int j = idx&127;
        int ent = row0 + r; int agent = ent/NEN;
        float v = (j < 64) ? SFb[(size_t)agent*64+j] : ESC[(size_t)ent*64 + (j-64)];
        atfT[j][r] = v;
    }
    __syncthreads();
    {   // layer1: j = tid&127 (coalesced W1), rr = tid>>7 -> rows rr*8..+7
        int j = tid & 127, rr = tid >> 7;
        float bb = b1[j];
        float acc[8];
#pragma unroll
        for (int r = 0; r < 8; ++r) acc[r] = bb;
#pragma unroll 8
        for (int k = 0; k < 128; ++k) {
            float w = W1[k*128 + j];
            float4 a0 = *(const float4*)&atfT[k][rr*8];
            float4 a1 = *(const float4*)&atfT[k][rr*8 + 4];
            acc[0] = fmaf(a0.x, w, acc[0]);
            acc[1] = fmaf(a0.y, w, acc[1]);
            acc[2] = fmaf(a0.z, w, acc[2]);
            acc[3] = fmaf(a0.w, w, acc[3]);
            acc[4] = fmaf(a1.x, w, acc[4]);
            acc[5] = fmaf(a1.y, w, acc[5]);
            acc[6] = fmaf(a1.z, w, acc[6]);
            acc[7] = fmaf(a1.w, w, acc[7]);
        }
        float4 o0 = make_float4(fmaxf(acc[0],0.f), fmaxf(acc[1],0.f),
                                fmaxf(acc[2],0.f), fmaxf(acc[3],0.f));
        float4 o1 = make_float4(fmaxf(acc[4],0.f), fmaxf(acc[5],0.f),
                                fmaxf(acc[6],0.f), fmaxf(acc[7],0.f));
        *(float4*)&h1T[j][rr*8]     = o0;
        *(float4*)&h1T[j][rr*8 + 4] = o1;
    }
    __syncthreads();
    {   // layer2: j2 = tid&63 (coalesced W2), rr2 = tid>>6 -> rows rr2*4..+3
        int j2 = tid & 63, rr2 = tid >> 6;
        float bb = b2[j2];
        float acc[4] = {bb, bb, bb, bb};
#pragma unroll 8
        for (int k = 0; k < 128; ++k) {
            float w = W2[k*64 + j2];
            float4 p = *(const float4*)&h1T[k][rr2*4];
            acc[0] = fmaf(p.x, w, acc[0]);
            acc[1] = fmaf(p.y, w, acc[1]);
            acc[2] = fmaf(p.z, w, acc[2]);
            acc[3] = fmaf(p.w, w, acc[3]);
        }
#pragma unroll
        for (int r = 0; r < 4; ++r) h2[rr2*4+r][j2] = fmaxf(acc[r], 0.f);
    }
    __syncthreads();
    {   // layer3: 16 rows, 16 lanes/row
        int r3 = tid >> 4, l3 = tid & 15;
        float s = 0.f;
#pragma unroll
        for (int q = 0; q < 4; ++q) s = fmaf(h2[r3][l3 + 16*q], W3[l3 + 16*q], s);
#pragma unroll
        for (int m = 1; m < 16; m <<= 1) s += __shfl_xor(s, m, 64);
        if (l3 == 0) {
            int ent = row0 + r3; int agent = ent/NEN; int e = ent%NEN;
            out[(size_t)agent*16 + 6 + e] = s + b3[0];
        }
    }
}

extern "C" void kernel_launch(void* const* d_in, const int* in_sizes, int n_in,
                              void* d_out, int out_size, void* d_ws, size_t ws_size,
                              hipStream_t stream) {
    const float* own  = (const float*)d_in[0];
    const float* ef   = (const float*)d_in[1];
    const float* af   = (const float*)d_in[2];
    const float* W_e1 = (const float*)d_in[3];
    const float* W_e2 = (const float*)d_in[4];
    const float* W_a1 = (const float*)d_in[5];
    const float* W_a2 = (const float*)d_in[6];
    const float* W_f1 = (const float*)d_in[7];
    const float* W_f2 = (const float*)d_in[8];
    const float* W_ie1= (const float*)d_in[9];
    const float* W_ie2= (const float*)d_in[10];
    const float* W_ie3= (const float*)d_in[11];
    const float* W_ia1= (const float*)d_in[12];
    const float* W_ia2= (const float*)d_in[13];
    const float* W_ia3= (const float*)d_in[14];
    const float* W_oa1= (const float*)d_in[15];
    const float* b_oa1= (const float*)d_in[16];
    const float* W_oa2= (const float*)d_in[17];
    const float* b_oa2= (const float*)d_in[18];
    const float* W_at1= (const float*)d_in[19];
    const float* b_at1= (const float*)d_in[20];
    const float* W_at2= (const float*)d_in[21];
    const float* b_at2= (const float*)d_in[22];
    const float* W_at3= (const float*)d_in[23];
    const float* b_at3= (const float*)d_in[24];
    float* out = (float*)d_out;
    float* wsf = (float*)d_ws;
    double* Sd = (double*)d_ws;

    size_t o = (size_t)NDOUBLES*2;
    float*  X_E  = wsf + o; o += (size_t)NEE*128;
    float*  X_A  = wsf + o; o += (size_t)NAE*128;
    float*  F1   = wsf + o; o += (size_t)NAG*128;
    float*  SFb  = wsf + o; o += (size_t)NAG*64;
    float*  VT_IE = wsf + o; o += (size_t)NAG*128;
    float*  VT_IA = wsf + o; o += (size_t)NAG*128;
    float*  XI   = wsf + o; o += (size_t)NEE*128;
    float*  Z_IE = wsf + o; o += (size_t)NEE*2;
    float*  Z_IA = wsf + o; o += (size_t)NEE*2;
    float*  ESC  = wsf + o; o += (size_t)NEE*64;   // e_scalar (pair_m2 of X_E)

    double* S_E1 = Sd + DOFF_SE1;  double* S_E2 = Sd + DOFF_SE2;
    double* S_A1 = Sd + DOFF_SA1;  double* S_A2 = Sd + DOFF_SA2;
    double* S_F1 = Sd + DOFF_SF1;  double* S_F2 = Sd + DOFF_SF2;
    double* S_IE1= Sd + DOFF_SIE1; double* S_IE2= Sd + DOFF_SIE2;
    double* S_IA1= Sd + DOFF_SIA1; double* S_IA2= Sd + DOFF_SIA2;
    double* S_IE3= Sd + DOFF_SIE3; double* S_IA3= Sd + DOFF_SIA3;

    const double invRe = 1.0/(double)(NEE*2);
    const double invRa = 1.0/(double)(NAE*2);
    const double invRf = 1.0/(double)(NAG*2);

    hipMemsetAsync(Sd, 0, (size_t)NDOUBLES*sizeof(double), stream);

    k_build_both<<<NBLK_BE + NBLK_BA, 256, 0, stream>>>(
        ef, af, own, W_e1, W_a1, X_E, X_A, S_E1, S_A1);
    k_pair_both<<<NBLK_PE + NBLK_PA, 256, 0, stream>>>(
        X_E, S_E1, S_E2, W_e2, invRe, X_A, S_A1, S_A2, W_a2, invRa);
    k_finalize_pair<<<NEE*32/256, 256, 0, stream>>>(X_E, S_E2, invRe, ESC);
    k_pool_f1<<<NAG/4, 256, 0, stream>>>(X_E, X_A, S_A2, invRa, W_f1, F1, S_F1);
    k_pair_layer<<<NAG/16, 256, 0, stream>>>(F1, S_F1, S_F2, W_f2, invRf);
    k_vf_vtop<<<NAG/4, 256, 0, stream>>>(F1, S_F2, SFb, W_ie1, W_ia1, VT_IE, VT_IA, invRf);
    // e-importance chain
    k_imp1<<<NEE/8, 256, 0, stream>>>(X_E, VT_IE, W_ie1, XI, S_IE1);
    k_pair_layer<<<NEE/16, 256, 0, stream>>>(XI, S_IE1, S_IE2, W_ie2, invRe);
    k_imp3<<<NEE/16, 256, 0, stream>>>(XI, S_IE2, W_ie3, Z_IE, S_IE3, invRe);
    // a-importance chain (same cat input; XI reused)
    k_imp1<<<NEE/8, 256, 0, stream>>>(X_E, VT_IA, W_ia1, XI, S_IA1);
    k_pair_layer<<<NEE/16, 256, 0, stream>>>(XI, S_IA1, S_IA2, W_ia2, invRe);
    k_imp3<<<NEE/16, 256, 0, stream>>>(XI, S_IA2, W_ia3, Z_IA, S_IA3, invRe);

    k_final_small<<<NAG/4, 256, 0, stream>>>(Z_IE, Z_IA, S_IE3, S_IA3, SFb,
                                             W_oa1, b_oa1, W_oa2, b_oa2, out, invRe);
    k_attn<<<NEE/16, 256, 0, stream>>>(SFb, ESC, W_at1, b_at1, W_at2, b_at2,
                                       W_at3, b_at3, out);
}